// Round 1
// 193.517 us; speedup vs baseline: 1.0175x; 1.0175x over previous
//
#include <hip/hip_runtime.h>

// ============================================================================
// MultiHeadCrossAttention on MI355X (gfx950) — round 9
//   B=2, SQ=SK=2048, H=16, D=64, EMB=CTX=INNER=1024, fp32 in/out.
//
// 4 dispatches:
//   1. cvt6: all fp32->bf16 conversions
//   2. gemm_qkv: 128x128 tiles (m97 shape: 4 waves 2x2, each 64x64, acc 4x4),
//      grid (256,3) = 768 blocks = 3/CU, XOR-swizzled LDS,
//      q (softmax scale folded), k (+fused LN), vT (key-permuted cols)
//   3. flash2: 8-wave blocks, 2-way K-split, dual interleaved S^T chains,
//      l computed by ones-A MFMA (no serial VALU chain), O^T=V^T·P^T
//   4. gemm_out: 64x64 tiles (1024 blocks = 4/CU), XOR-swizzled LDS
// ============================================================================

typedef __attribute__((ext_vector_type(8)))  short bf16x8;
typedef __attribute__((ext_vector_type(4)))  short bf16x4;
typedef __attribute__((ext_vector_type(4)))  float f32x4;
typedef __attribute__((ext_vector_type(16))) float f32x16;
typedef __attribute__((ext_vector_type(4)))  unsigned int u32x4;

#define SM_SCALE 0.18033688f   // 0.125 * log2(e), folded into q at LN

typedef __attribute__((address_space(1))) const void cg_void;
typedef __attribute__((address_space(3))) void lds_void_t;

__device__ __forceinline__ void gl_lds16(const void* g, void* l){
  __builtin_amdgcn_global_load_lds((cg_void*)g, (lds_void_t*)l, 16, 0, 0);
}

__device__ __forceinline__ short f2b(float f){
  unsigned int u;
  __builtin_memcpy(&u, &f, 4);
  u += 0x7fffu + ((u >> 16) & 1u);   // round-to-nearest-even
  return (short)(u >> 16);
}

// ---------------------------------------------------------------------------
// Fused fp32 -> bf16 convert of all six inputs (12M elems, 4 per thread).
// ---------------------------------------------------------------------------
__global__ __launch_bounds__(256) void cvt6_kernel(
    const float* __restrict__ emb, const float* __restrict__ ctx,
    const float* __restrict__ Wq, const float* __restrict__ Wk,
    const float* __restrict__ Wv, const float* __restrict__ Wu,
    short* __restrict__ o_emb, short* __restrict__ o_ctx,
    short* __restrict__ o_wq, short* __restrict__ o_wk,
    short* __restrict__ o_wv, short* __restrict__ o_wu)
{
  const long M1 = 1024L * 1024L, M4 = 4L * M1;
  long e = ((long)blockIdx.x * 256 + threadIdx.x) * 4;
  if (e >= 12L * M1) return;
  const float* src; short* dst; long off;
  if      (e <     M4)      { src = emb; dst = o_emb; off = e;           }
  else if (e < 2 * M4)      { src = ctx; dst = o_ctx; off = e - M4;      }
  else if (e < 2 * M4 + M1) { src = Wq;  dst = o_wq;  off = e - 2 * M4;  }
  else if (e < 2 * M4 + 2*M1){src = Wk;  dst = o_wk;  off = e - 2*M4 - M1;}
  else if (e < 2 * M4 + 3*M1){src = Wv;  dst = o_wv;  off = e - 2*M4 - 2*M1;}
  else                      { src = Wu;  dst = o_wu;  off = e - 2*M4 - 3*M1;}
  f32x4 v = *(const f32x4*)(src + off);
  bf16x4 o;
  o[0] = f2b(v[0]); o[1] = f2b(v[1]); o[2] = f2b(v[2]); o[3] = f2b(v[3]);
  *(bf16x4*)(dst + off) = o;
}

// ---------------------------------------------------------------------------
// Fused QKV projections. Grid (256, 3); blockIdx.y = task.
//   task 0: q = (emb@Wq^T -> LN)*SM_SCALE   (bm fastest, x&31)
//   task 1: k = ctx@Wk^T + LN               (bm fastest)
//   task 2: vT = Wv@ctx^T, key-permuted cols (bn fastest, x&31)
// 128x128 tile (m97 shape), BK=64, 4 waves in 2x2, each 64x64 (4x4 MFMA
// 16x16x32) -> 32 FLOP per LDS byte (vs 21.3 at the old 128x64 shape).
// Wave N-span = 64 = one head chunk -> LN stays wave-local (4 j-frags,
// shfl-xor over r16, unchanged). 32 KB LDS, 768 blocks = 3 blocks/CU =
// 12 waves/CU (the proven m97 occupancy point).
// ---------------------------------------------------------------------------
__global__ __launch_bounds__(256, 3) void gemm_qkv_kernel(
    const short* __restrict__ embh, const short* __restrict__ ctxh,
    const short* __restrict__ Wqh, const short* __restrict__ Wkh,
    const short* __restrict__ Wvh,
    short* __restrict__ qo, short* __restrict__ ko, short* __restrict__ vto,
    const float* __restrict__ qw, const float* __restrict__ qb,
    const float* __restrict__ kw, const float* __restrict__ kb)
{
  const int K = 1024;
  __shared__ short As[128 * 64];   // 16 KB
  __shared__ short Bs[128 * 64];   // 16 KB
  const int tid  = threadIdx.x;
  const int wave = tid >> 6, lane = tid & 63;
  const int quad = lane >> 4, r16 = lane & 15;
  const int wm = (wave >> 1) * 64, wn = (wave & 1) * 64;

  const int task = blockIdx.y;
  int bn, bm, N;
  const short *A, *B;
  if (task == 2){
    bn = (blockIdx.x & 31) * 128; bm = (blockIdx.x >> 5) * 128; N = 4096;
    A = Wvh; B = ctxh;
  } else {
    bm = (blockIdx.x & 31) * 128; bn = (blockIdx.x >> 5) * 128; N = 1024;
    A = task ? ctxh : embh; B = task ? Wkh : Wqh;
  }

  f32x4 acc[4][4];
#pragma unroll
  for (int i = 0; i < 4; i++)
#pragma unroll
    for (int j = 0; j < 4; j++)
      acc[i][j] = (f32x4){0.f, 0.f, 0.f, 0.f};

  const int sr7 = (lane >> 3) & 7;
  const size_t arow = (size_t)(bm + wave * 8 + (lane >> 3)) * K
                      + (((lane & 7) ^ sr7) * 8);
  const size_t brow = (size_t)(bn + wave * 8 + (lane >> 3)) * K
                      + (((lane & 7) ^ sr7) * 8);
  const int sw = ((quad ^ (r16 & 7)) << 3);

  for (int k0 = 0; k0 < K; k0 += 64){
#pragma unroll
    for (int i = 0; i < 4; i++)
      gl_lds16(A + arow + (size_t)32 * i * K + k0, &As[wave * 512 + i * 2048]);
#pragma unroll
    for (int i = 0; i < 4; i++)
      gl_lds16(B + brow + (size_t)32 * i * K + k0, &Bs[wave * 512 + i * 2048]);
    __syncthreads();
#pragma unroll
    for (int kk = 0; kk < 2; kk++){
      const int off = sw ^ (kk << 5);
      bf16x8 af[4], bq[4];
#pragma unroll
      for (int i = 0; i < 4; i++)
        af[i] = *(const bf16x8*)(&As[(wm + i*16 + r16) * 64 + off]);
#pragma unroll
      for (int j = 0; j < 4; j++)
        bq[j] = *(const bf16x8*)(&Bs[(wn + j*16 + r16) * 64 + off]);
#pragma unroll
      for (int i = 0; i < 4; i++)
#pragma unroll
        for (int j = 0; j < 4; j++)
          acc[i][j] = __builtin_amdgcn_mfma_f32_16x16x32_bf16(af[i], bq[j], acc[i][j], 0, 0, 0);
    }
    __syncthreads();
  }

  if (task < 2){
    short* Ch = task ? ko : qo;
    const float* lw = task ? kw : qw;
    const float* lb = task ? kb : qb;
    const float post = task ? 1.0f : SM_SCALE;   // fold softmax scale into q
    float wv[4], bv[4];
#pragma unroll
    for (int j = 0; j < 4; j++){
      wv[j] = lw[j*16 + r16] * post;
      bv[j] = lb[j*16 + r16] * post;
    }
#pragma unroll
    for (int i = 0; i < 4; i++){
#pragma unroll
      for (int t = 0; t < 4; t++){
        float a[4];
#pragma unroll
        for (int j = 0; j < 4; j++) a[j] = acc[i][j][t];
        float s = a[0] + a[1] + a[2] + a[3];
        s += __shfl_xor(s, 1); s += __shfl_xor(s, 2);
        s += __shfl_xor(s, 4); s += __shfl_xor(s, 8);
        const float mu = s * 0.015625f;
        float d[4], sq = 0.f;
#pragma unroll
        for (int j = 0; j < 4; j++){ d[j] = a[j] - mu; sq += d[j]*d[j]; }
        sq += __shfl_xor(sq, 1); sq += __shfl_xor(sq, 2);
        sq += __shfl_xor(sq, 4); sq += __shfl_xor(sq, 8);
        const float si = rsqrtf(sq * 0.015625f + 1e-5f);
        const size_t row = (size_t)(bm + wm + i*16 + quad*4 + t);
#pragma unroll
        for (int j = 0; j < 4; j++)
          Ch[row * 1024 + (bn + wn + j*16 + r16)] = f2b(d[j] * si * wv[j] + bv[j]);
      }
    }
  } else {
#pragma unroll
    for (int i = 0; i < 4; i++){
#pragma unroll
      for (int j = 0; j < 4; j++){
        // permute token index within its 32-group into PV fragment order
        const int p = (r16 & 3) | ((j & 1) << 2) | (((r16 >> 2) & 1) << 3)
                      | (((r16 >> 3) & 1) << 4);
        const int col = ((bn + wn + j*16 + r16) & ~31) | p;
#pragma unroll
        for (int t = 0; t < 4; t++){
          const size_t row = (size_t)(bm + wm + i*16 + quad*4 + t);
          vto[row * (size_t)N + col] = f2b(acc[i][j][t]);
        }
      }
    }
  }
}

// ---------------------------------------------------------------------------
// out = ao @ Wu^T + bu. M=4096, N=K=1024, fp32 out.
// 64x64 tile, 256 threads, 4 waves 2x2 each 32x32 (2x2 MFMA). 16 KB LDS ->
// grid 1024 blocks = 4 blocks/CU: block-level overlap hides barrier drains.
// XOR-swizzled LDS. Grid (64, 16): bm fastest (same-A blocks share XCD).
// ---------------------------------------------------------------------------
__global__ __launch_bounds__(256, 4) void gemm_out_kernel(
    const short* __restrict__ A, const short* __restrict__ B,
    float* __restrict__ Cf, const float* __restrict__ bias)
{
  const int K = 1024, N = 1024;
  __shared__ short As[64 * 64];   // 8 KB
  __shared__ short Bs[64 * 64];   // 8 KB
  const int tid  = threadIdx.x;
  const int wave = tid >> 6, lane = tid & 63;
  const int quad = lane >> 4, r16 = lane & 15;
  const int wm = (wave >> 1) * 32, wn = (wave & 1) * 32;
  const int bm = blockIdx.x * 64, bn = blockIdx.y * 64;

  f32x4 acc[2][2];
#pragma unroll
  for (int i = 0; i < 2; i++)
#pragma unroll
    for (int j = 0; j < 2; j++)
      acc[i][j] = (f32x4){0.f, 0.f, 0.f, 0.f};

  const int sr7 = (lane >> 3) & 7;
  const size_t arow = (size_t)(bm + wave * 8 + (lane >> 3)) * K
                      + (((lane & 7) ^ sr7) * 8);
  const size_t brow = (size_t)(bn + wave * 8 + (lane >> 3)) * K
                      + (((lane & 7) ^ sr7) * 8);
  const int sw = ((quad ^ (r16 & 7)) << 3);

  for (int k0 = 0; k0 < K; k0 += 64){
#pragma unroll
    for (int i = 0; i < 2; i++){
      gl_lds16(A + arow + (size_t)32 * i * K + k0, &As[wave * 512 + i * 2048]);
      gl_lds16(B + brow + (size_t)32 * i * K + k0, &Bs[wave * 512 + i * 2048]);
    }
    __syncthreads();
#pragma unroll
    for (int kk = 0; kk < 2; kk++){
      const int off = sw ^ (kk << 5);
      bf16x8 af[2], bq[2];
#pragma unroll
      for (int i = 0; i < 2; i++)
        af[i] = *(const bf16x8*)(&As[(wm + i*16 + r16) * 64 + off]);
#pragma unroll
      for (int j = 0; j < 2; j++)
        bq[j] = *(const bf16x8*)(&Bs[(wn + j*16 + r16) * 64 + off]);
#pragma unroll
      for (int i = 0; i < 2; i++)
#pragma unroll
        for (int j = 0; j < 2; j++)
          acc[i][j] = __builtin_amdgcn_mfma_f32_16x16x32_bf16(af[i], bq[j], acc[i][j], 0, 0, 0);
    }
    __syncthreads();
  }

#pragma unroll
  for (int i = 0; i < 2; i++){
#pragma unroll
    for (int j = 0; j < 2; j++){
      const int col = bn + wn + j*16 + r16;
#pragma unroll
      for (int t = 0; t < 4; t++){
        const size_t row = (size_t)(bm + wm + i*16 + quad*4 + t);
        Cf[row * N + col] = acc[i][j][t] + bias[col];
      }
    }
  }
}

// ---------------------------------------------------------------------------
// MFMA flash attention v5 — 8 waves, 2-way K-split, MFMA-computed l.
//   Grid (16 h, 16 qb, 2 b): h innermost -> per-XCD K/V L2 reuse.
//   wave = half*4 + wg. Per half: double-buffered 64-key tiles (XOR-swizzled).
//   Per iter: hoist 8 kf reads, dual interleaved S^T=K·Q^T chains; per s32:
//   exp2 (scale pre-folded into q) -> pack (bit-add + v_perm) -> PV MFMAs
//   plus l-MFMA with constant ones A-operand (no serial VALU sum chain).
//   End: halves combine through LDS (stride-33 floats).
// ---------------------------------------------------------------------------
__global__ __launch_bounds__(512, 4) void flash2_kernel(
    const short* __restrict__ Q, const short* __restrict__ K,
    const short* __restrict__ Vt, short* __restrict__ O)
{
  __shared__ __align__(16) long long smem8[8192];   // 64 KB
  short* Ks  = (short*)smem8;        // 4 bufs x 4096 shorts: [half*2+buf]
  short* Vts = Ks + 16384;
  float* scr = (float*)smem8;        // epilogue reuse

  const int tid = threadIdx.x;
  const int wave = tid >> 6, lane = tid & 63;
  const int half = wave >> 2, wg = wave & 3;
  const int hh = lane >> 5, q5 = lane & 31;
  const int h = blockIdx.x, qb = blockIdx.y, b = blockIdx.z;
  const int q0 = qb * 128 + wg * 32;

  const size_t kbase = ((size_t)b * 2048) * 1024 + (size_t)h * 64;
  const size_t vbase = ((size_t)h * 64) * 4096 + (size_t)b * 2048;

  // Q B-frags: lane holds Q[q0+q5][c*16 + hh*8 + j]  (pre-scaled by SM_SCALE)
  bf16x8 qf[4];
  {
    const size_t qrow = ((size_t)b * 2048 + q0 + q5) * 1024 + (size_t)h * 64;
#pragma unroll
    for (int c = 0; c < 4; c++)
      qf[c] = *(const bf16x8*)(Q + qrow + c * 16 + hh * 8);
  }

  bf16x8 onesf;
#pragma unroll
  for (int j = 0; j < 8; j++) onesf[j] = (short)0x3F80;   // bf16 1.0

  f32x16 oacc[2], oaccl;
#pragma unroll
  for (int t = 0; t < 16; t++){ oacc[0][t] = 0.f; oacc[1][t] = 0.f; oaccl[t] = 0.f; }

  const int srow = lane >> 3;
  const int csrc = ((lane & 7) ^ srow) * 8;
  const int wr0 = wg * 16;

#define STAGE(bufi, kt)                                                         \
  {                                                                             \
    const short* ks = K + kbase + (size_t)((kt) * 64 + wr0 + srow) * 1024 + csrc; \
    const short* vs = Vt + vbase + (size_t)(wr0 + srow) * 4096 + (kt) * 64 + csrc; \
    short* kd = Ks  + (half * 2 + (bufi)) * 4096 + wr0 * 64;                    \
    short* vd = Vts + (half * 2 + (bufi)) * 4096 + wr0 * 64;                    \
    gl_lds16(ks,            kd);                                                \
    gl_lds16(ks + 8 * 1024, kd + 512);                                          \
    gl_lds16(vs,            vd);                                                \
    gl_lds16(vs + 8 * 4096, vd + 512);                                          \
  }

  STAGE(0, half)

  for (int i = 0; i < 16; i++){
    const int buf = i & 1;
    __syncthreads();                         // staging(buf) drained; buf^1 free
    if (i + 1 < 16) STAGE(buf ^ 1, 2 * (i + 1) + half)

    const short* kb_l = Ks  + (half * 2 + buf) * 4096;
    const short* vb_l = Vts + (half * 2 + buf) * 4096;

    // ---- hoist all 8 kf reads; run both 32-key S chains interleaved ----
    bf16x8 kf[2][4];
#pragma unroll
    for (int s32 = 0; s32 < 2; s32++){
      const int key = s32 * 32 + q5;
#pragma unroll
      for (int c = 0; c < 4; c++)
        kf[s32][c] = *(const bf16x8*)(&kb_l[key * 64 + (((2*c + hh) ^ (key & 7)) << 3)]);
    }
    f32x16 sacc[2];
#pragma unroll
    for (int t = 0; t < 16; t++){ sacc[0][t] = 0.f; sacc[1][t] = 0.f; }
#pragma unroll
    for (int c = 0; c < 4; c++){
      sacc[0] = __builtin_amdgcn_mfma_f32_32x32x16_bf16(kf[0][c], qf[c], sacc[0], 0, 0, 0);
      sacc[1] = __builtin_amdgcn_mfma_f32_32x32x16_bf16(kf[1][c], qf[c], sacc[1], 0, 0, 0);
    }

#pragma unroll
    for (int s32 = 0; s32 < 2; s32++){
      // ---- P = exp2(S^T) (scale pre-folded); pack via bit-add + v_perm ----
      unsigned int pu[16];
#pragma unroll
      for (int t = 0; t < 16; t++){
        const float e = __builtin_amdgcn_exp2f(sacc[s32][t]);
        unsigned int u; __builtin_memcpy(&u, &e, 4);
        pu[t] = u + 0x8000u;                 // round into top 16 bits
      }

      // ---- O^T += V^T·P^T ; l += ones·P^T (const-A MFMA, no LDS) ----
#pragma unroll
      for (int c = 0; c < 2; c++){
        u32x4 tmp;
        tmp[0] = __builtin_amdgcn_perm(pu[4*c + 1], pu[4*c + 0], 0x07060302u);
        tmp[1] = __builtin_amdgcn_perm(pu[4*c + 3], pu[4*c + 2], 0x07060302u);
        tmp[2] = __builtin_amdgcn_perm(pu[8 + 4*c + 1], pu[8 + 4*c + 0], 0x07060302u);
        tmp[3] = __builtin_amdgcn_perm(pu[8 + 4*c + 3], pu[8 + 4*c + 2], 0x07060302u);
        bf16x8 pf; __builtin_memcpy(&pf, &tmp, 16);
#pragma unroll
        for (int mt = 0; mt < 2; mt++){
          const int d = mt * 32 + q5;
          bf16x8 vf = *(const bf16x8*)(&vb_l[d * 64 + (((s32*4 + 2*c + hh) ^ (d & 7)) << 3)]);
          oacc[mt] = __builtin_amdgcn_mfma_f32_32x32x16_bf16(vf, pf, oacc[mt], 0, 0, 0);
        }
        oaccl = __builtin_amdgcn_mfma_f32_32x32x16_bf16(onesf, pf, oaccl, 0, 0, 0);
      }
    }
  }

  // ---- combine halves through LDS, then store O[q][d] = O^T / l ----
  // oaccl: every reg holds l(q5) (all 32 output rows identical).
  const float lhalf = oaccl[0];
  __syncthreads();                           // all buffer reads done
  float* base = scr + (wg * 64 + lane) * 33;
  if (half == 1){
#pragma unroll
    for (int t = 0; t < 16; t++){ base[t] = oacc[0][t]; base[16 + t] = oacc[1][t]; }
    scr[8448 + wg * 64 + lane] = lhalf;
  }
  __syncthreads();
  if (half == 0){
    const float l2 = scr[8448 + wg * 64 + lane];
    const float linv = 1.0f / (lhalf + l2);
    const size_t orow = ((size_t)b * 2048 + q0 + q5) * 1024 + (size_t)h * 64;
#pragma unroll
    for (int mt = 0; mt < 2; mt++){
#pragma unroll
      for (int g = 0; g < 4; g++){
        bf16x4 o4;
#pragma unroll
        for (int u = 0; u < 4; u++)
          o4[u] = f2b((oacc[mt][g*4 + u] + base[mt*16 + g*4 + u]) * linv);
        *(bf16x4*)(O + orow + mt*32 + g*8 + 4*hh) = o4;
      }
    }
  }
}
#undef STAGE

// ---------------------------------------------------------------------------
extern "C" void kernel_launch(void* const* d_in, const int* in_sizes, int n_in,
                              void* d_out, int out_size, void* d_ws, size_t ws_size,
                              hipStream_t stream) {
  const float* emb  = (const float*)d_in[0];
  const float* ctx  = (const float*)d_in[1];
  const float* Wq   = (const float*)d_in[2];
  const float* Wk   = (const float*)d_in[3];
  const float* Wv   = (const float*)d_in[4];
  const float* Wu   = (const float*)d_in[5];
  const float* bu   = (const float*)d_in[6];
  const float* qn_w = (const float*)d_in[7];
  const float* qn_b = (const float*)d_in[8];
  const float* kn_w = (const float*)d_in[9];
  const float* kn_b = (const float*)d_in[10];
  float* out = (float*)d_out;

  const size_t BIG = (size_t)4096 * 1024;
  const size_t WSZ = (size_t)1024 * 1024;
  short* ws   = (short*)d_ws;
  short* embh = ws;
  short* ctxh = embh + BIG;
  short* Wqh  = ctxh + BIG;
  short* Wkh  = Wqh + WSZ;
  short* Wvh  = Wkh + WSZ;
  short* Wuh  = Wvh + WSZ;
  short* qh   = Wuh + WSZ;
  short* kh   = qh + BIG;
  short* vth  = kh + BIG;    // V^T [inner][token], key-permuted columns
  short* aoh  = vth + BIG;

  cvt6_kernel<<<12288, 256, 0, stream>>>(emb, ctx, Wq, Wk, Wv, Wu,
                                         embh, ctxh, Wqh, Wkh, Wvh, Wuh);

  gemm_qkv_kernel<<<dim3(256, 3), 256, 0, stream>>>(
      embh, ctxh, Wqh, Wkh, Wvh, qh, kh, vth,
      qn_w, qn_b, kn_w, kn_b);

  flash2_kernel<<<dim3(16, 16, 2), 512, 0, stream>>>(qh, kh, vth, aoh);

  gemm_out_kernel<<<dim3(64, 16), 256, 0, stream>>>(aoh, Wuh, out, bu);
}

// Round 2
// 190.789 us; speedup vs baseline: 1.0320x; 1.0143x over previous
//
#include <hip/hip_runtime.h>

// ============================================================================
// MultiHeadCrossAttention on MI355X (gfx950) — round 10
//   B=2, SQ=SK=2048, H=16, D=64, EMB=CTX=INNER=1024, fp32 in/out.
//
// 4 dispatches:
//   1. cvt6: all fp32->bf16 conversions
//   2. gemm_qkv: 128x128 tiles (m97 shape), XOR-swizzled LDS,
//      q (softmax scale folded), k (+fused LN), vT (key-permuted cols)
//   3. flash2 v6: 4-wave blocks, 2-way K-split, 64 q-rows PER WAVE
//      (kf/vf LDS reads amortized over 2 q-groups -> LDS reads/MFMA halved),
//      l via VALU partial trees (no l-MFMA), O^T=V^T·P^T
//   4. gemm_out: 64x64 tiles (1024 blocks = 4/CU), XOR-swizzled LDS
// ============================================================================

typedef __attribute__((ext_vector_type(8)))  short bf16x8;
typedef __attribute__((ext_vector_type(4)))  short bf16x4;
typedef __attribute__((ext_vector_type(4)))  float f32x4;
typedef __attribute__((ext_vector_type(16))) float f32x16;
typedef __attribute__((ext_vector_type(4)))  unsigned int u32x4;

#define SM_SCALE 0.18033688f   // 0.125 * log2(e), folded into q at LN

typedef __attribute__((address_space(1))) const void cg_void;
typedef __attribute__((address_space(3))) void lds_void_t;

__device__ __forceinline__ void gl_lds16(const void* g, void* l){
  __builtin_amdgcn_global_load_lds((cg_void*)g, (lds_void_t*)l, 16, 0, 0);
}

__device__ __forceinline__ short f2b(float f){
  unsigned int u;
  __builtin_memcpy(&u, &f, 4);
  u += 0x7fffu + ((u >> 16) & 1u);   // round-to-nearest-even
  return (short)(u >> 16);
}

// ---------------------------------------------------------------------------
// Fused fp32 -> bf16 convert of all six inputs (12M elems, 4 per thread).
// ---------------------------------------------------------------------------
__global__ __launch_bounds__(256) void cvt6_kernel(
    const float* __restrict__ emb, const float* __restrict__ ctx,
    const float* __restrict__ Wq, const float* __restrict__ Wk,
    const float* __restrict__ Wv, const float* __restrict__ Wu,
    short* __restrict__ o_emb, short* __restrict__ o_ctx,
    short* __restrict__ o_wq, short* __restrict__ o_wk,
    short* __restrict__ o_wv, short* __restrict__ o_wu)
{
  const long M1 = 1024L * 1024L, M4 = 4L * M1;
  long e = ((long)blockIdx.x * 256 + threadIdx.x) * 4;
  if (e >= 12L * M1) return;
  const float* src; short* dst; long off;
  if      (e <     M4)      { src = emb; dst = o_emb; off = e;           }
  else if (e < 2 * M4)      { src = ctx; dst = o_ctx; off = e - M4;      }
  else if (e < 2 * M4 + M1) { src = Wq;  dst = o_wq;  off = e - 2 * M4;  }
  else if (e < 2 * M4 + 2*M1){src = Wk;  dst = o_wk;  off = e - 2*M4 - M1;}
  else if (e < 2 * M4 + 3*M1){src = Wv;  dst = o_wv;  off = e - 2*M4 - 2*M1;}
  else                      { src = Wu;  dst = o_wu;  off = e - 2*M4 - 3*M1;}
  f32x4 v = *(const f32x4*)(src + off);
  bf16x4 o;
  o[0] = f2b(v[0]); o[1] = f2b(v[1]); o[2] = f2b(v[2]); o[3] = f2b(v[3]);
  *(bf16x4*)(dst + off) = o;
}

// ---------------------------------------------------------------------------
// Fused QKV projections. Grid (256, 3); blockIdx.y = task.
//   task 0: q = (emb@Wq^T -> LN)*SM_SCALE   (bm fastest, x&31)
//   task 1: k = ctx@Wk^T + LN               (bm fastest)
//   task 2: vT = Wv@ctx^T, key-permuted cols (bn fastest, x&31)
// 128x128 tile (m97 shape), BK=64, 4 waves in 2x2, each 64x64 (4x4 MFMA
// 16x16x32). Wave N-span = 64 = one head chunk -> LN stays wave-local.
// 32 KB LDS, 768 blocks = 3 blocks/CU = 12 waves/CU.
// ---------------------------------------------------------------------------
__global__ __launch_bounds__(256, 3) void gemm_qkv_kernel(
    const short* __restrict__ embh, const short* __restrict__ ctxh,
    const short* __restrict__ Wqh, const short* __restrict__ Wkh,
    const short* __restrict__ Wvh,
    short* __restrict__ qo, short* __restrict__ ko, short* __restrict__ vto,
    const float* __restrict__ qw, const float* __restrict__ qb,
    const float* __restrict__ kw, const float* __restrict__ kb)
{
  const int K = 1024;
  __shared__ short As[128 * 64];   // 16 KB
  __shared__ short Bs[128 * 64];   // 16 KB
  const int tid  = threadIdx.x;
  const int wave = tid >> 6, lane = tid & 63;
  const int quad = lane >> 4, r16 = lane & 15;
  const int wm = (wave >> 1) * 64, wn = (wave & 1) * 64;

  const int task = blockIdx.y;
  int bn, bm, N;
  const short *A, *B;
  if (task == 2){
    bn = (blockIdx.x & 31) * 128; bm = (blockIdx.x >> 5) * 128; N = 4096;
    A = Wvh; B = ctxh;
  } else {
    bm = (blockIdx.x & 31) * 128; bn = (blockIdx.x >> 5) * 128; N = 1024;
    A = task ? ctxh : embh; B = task ? Wkh : Wqh;
  }

  f32x4 acc[4][4];
#pragma unroll
  for (int i = 0; i < 4; i++)
#pragma unroll
    for (int j = 0; j < 4; j++)
      acc[i][j] = (f32x4){0.f, 0.f, 0.f, 0.f};

  const int sr7 = (lane >> 3) & 7;
  const size_t arow = (size_t)(bm + wave * 8 + (lane >> 3)) * K
                      + (((lane & 7) ^ sr7) * 8);
  const size_t brow = (size_t)(bn + wave * 8 + (lane >> 3)) * K
                      + (((lane & 7) ^ sr7) * 8);
  const int sw = ((quad ^ (r16 & 7)) << 3);

  for (int k0 = 0; k0 < K; k0 += 64){
#pragma unroll
    for (int i = 0; i < 4; i++)
      gl_lds16(A + arow + (size_t)32 * i * K + k0, &As[wave * 512 + i * 2048]);
#pragma unroll
    for (int i = 0; i < 4; i++)
      gl_lds16(B + brow + (size_t)32 * i * K + k0, &Bs[wave * 512 + i * 2048]);
    __syncthreads();
#pragma unroll
    for (int kk = 0; kk < 2; kk++){
      const int off = sw ^ (kk << 5);
      bf16x8 af[4], bq[4];
#pragma unroll
      for (int i = 0; i < 4; i++)
        af[i] = *(const bf16x8*)(&As[(wm + i*16 + r16) * 64 + off]);
#pragma unroll
      for (int j = 0; j < 4; j++)
        bq[j] = *(const bf16x8*)(&Bs[(wn + j*16 + r16) * 64 + off]);
#pragma unroll
      for (int i = 0; i < 4; i++)
#pragma unroll
        for (int j = 0; j < 4; j++)
          acc[i][j] = __builtin_amdgcn_mfma_f32_16x16x32_bf16(af[i], bq[j], acc[i][j], 0, 0, 0);
    }
    __syncthreads();
  }

  if (task < 2){
    short* Ch = task ? ko : qo;
    const float* lw = task ? kw : qw;
    const float* lb = task ? kb : qb;
    const float post = task ? 1.0f : SM_SCALE;   // fold softmax scale into q
    float wv[4], bv[4];
#pragma unroll
    for (int j = 0; j < 4; j++){
      wv[j] = lw[j*16 + r16] * post;
      bv[j] = lb[j*16 + r16] * post;
    }
#pragma unroll
    for (int i = 0; i < 4; i++){
#pragma unroll
      for (int t = 0; t < 4; t++){
        float a[4];
#pragma unroll
        for (int j = 0; j < 4; j++) a[j] = acc[i][j][t];
        float s = a[0] + a[1] + a[2] + a[3];
        s += __shfl_xor(s, 1); s += __shfl_xor(s, 2);
        s += __shfl_xor(s, 4); s += __shfl_xor(s, 8);
        const float mu = s * 0.015625f;
        float d[4], sq = 0.f;
#pragma unroll
        for (int j = 0; j < 4; j++){ d[j] = a[j] - mu; sq += d[j]*d[j]; }
        sq += __shfl_xor(sq, 1); sq += __shfl_xor(sq, 2);
        sq += __shfl_xor(sq, 4); sq += __shfl_xor(sq, 8);
        const float si = rsqrtf(sq * 0.015625f + 1e-5f);
        const size_t row = (size_t)(bm + wm + i*16 + quad*4 + t);
#pragma unroll
        for (int j = 0; j < 4; j++)
          Ch[row * 1024 + (bn + wn + j*16 + r16)] = f2b(d[j] * si * wv[j] + bv[j]);
      }
    }
  } else {
#pragma unroll
    for (int i = 0; i < 4; i++){
#pragma unroll
      for (int j = 0; j < 4; j++){
        // permute token index within its 32-group into PV fragment order
        const int p = (r16 & 3) | ((j & 1) << 2) | (((r16 >> 2) & 1) << 3)
                      | (((r16 >> 3) & 1) << 4);
        const int col = ((bn + wn + j*16 + r16) & ~31) | p;
#pragma unroll
        for (int t = 0; t < 4; t++){
          const size_t row = (size_t)(bm + wm + i*16 + quad*4 + t);
          vto[row * (size_t)N + col] = f2b(acc[i][j][t]);
        }
      }
    }
  }
}

// ---------------------------------------------------------------------------
// out = ao @ Wu^T + bu. M=4096, N=K=1024, fp32 out.
// 64x64 tile, 256 threads, 4 waves 2x2 each 32x32 (2x2 MFMA). 16 KB LDS ->
// grid 1024 blocks = 4 blocks/CU: block-level overlap hides barrier drains.
// XOR-swizzled LDS. Grid (64, 16): bm fastest (same-A blocks share XCD).
// ---------------------------------------------------------------------------
__global__ __launch_bounds__(256, 4) void gemm_out_kernel(
    const short* __restrict__ A, const short* __restrict__ B,
    float* __restrict__ Cf, const float* __restrict__ bias)
{
  const int K = 1024, N = 1024;
  __shared__ short As[64 * 64];   // 8 KB
  __shared__ short Bs[64 * 64];   // 8 KB
  const int tid  = threadIdx.x;
  const int wave = tid >> 6, lane = tid & 63;
  const int quad = lane >> 4, r16 = lane & 15;
  const int wm = (wave >> 1) * 32, wn = (wave & 1) * 32;
  const int bm = blockIdx.x * 64, bn = blockIdx.y * 64;

  f32x4 acc[2][2];
#pragma unroll
  for (int i = 0; i < 2; i++)
#pragma unroll
    for (int j = 0; j < 2; j++)
      acc[i][j] = (f32x4){0.f, 0.f, 0.f, 0.f};

  const int sr7 = (lane >> 3) & 7;
  const size_t arow = (size_t)(bm + wave * 8 + (lane >> 3)) * K
                      + (((lane & 7) ^ sr7) * 8);
  const size_t brow = (size_t)(bn + wave * 8 + (lane >> 3)) * K
                      + (((lane & 7) ^ sr7) * 8);
  const int sw = ((quad ^ (r16 & 7)) << 3);

  for (int k0 = 0; k0 < K; k0 += 64){
#pragma unroll
    for (int i = 0; i < 2; i++){
      gl_lds16(A + arow + (size_t)32 * i * K + k0, &As[wave * 512 + i * 2048]);
      gl_lds16(B + brow + (size_t)32 * i * K + k0, &Bs[wave * 512 + i * 2048]);
    }
    __syncthreads();
#pragma unroll
    for (int kk = 0; kk < 2; kk++){
      const int off = sw ^ (kk << 5);
      bf16x8 af[2], bq[2];
#pragma unroll
      for (int i = 0; i < 2; i++)
        af[i] = *(const bf16x8*)(&As[(wm + i*16 + r16) * 64 + off]);
#pragma unroll
      for (int j = 0; j < 2; j++)
        bq[j] = *(const bf16x8*)(&Bs[(wn + j*16 + r16) * 64 + off]);
#pragma unroll
      for (int i = 0; i < 2; i++)
#pragma unroll
        for (int j = 0; j < 2; j++)
          acc[i][j] = __builtin_amdgcn_mfma_f32_16x16x32_bf16(af[i], bq[j], acc[i][j], 0, 0, 0);
    }
    __syncthreads();
  }

#pragma unroll
  for (int i = 0; i < 2; i++){
#pragma unroll
    for (int j = 0; j < 2; j++){
      const int col = bn + wn + j*16 + r16;
#pragma unroll
      for (int t = 0; t < 4; t++){
        const size_t row = (size_t)(bm + wm + i*16 + quad*4 + t);
        Cf[row * N + col] = acc[i][j][t] + bias[col];
      }
    }
  }
}

// ---------------------------------------------------------------------------
// MFMA flash attention v6 — 4 waves, 2-way K-split, 64 q-rows per wave.
//   Grid (16 h, 16 qb, 2 b): h innermost -> per-XCD K/V L2 reuse.
//   wave = half*2 + wg; each wg owns 64 q (two 32-row groups qg=0,1).
//   kf/vf LDS fragments are q-independent -> read ONCE, used by both qg:
//   LDS reads per MFMA halved vs v5. l via VALU partial trees (frees the
//   l-MFMA and the 32-reg oaccl). 2 blocks/CU (128 KB LDS), 8 waves/CU.
//   Per iter: hoist 8 kf reads; 16 S-MFMAs (4 indep chains); exp2+pack;
//   16 PV MFMAs (vf read once per (s32,c,mt), both qg consume).
// ---------------------------------------------------------------------------
__global__ __launch_bounds__(256, 2) void flash2_kernel(
    const short* __restrict__ Q, const short* __restrict__ K,
    const short* __restrict__ Vt, short* __restrict__ O)
{
  __shared__ __align__(16) long long smem8[8192];   // 64 KB
  short* Ks  = (short*)smem8;        // 4 bufs x 4096 shorts: [half*2+buf]
  short* Vts = Ks + 16384;
  float* scr = (float*)smem8;        // epilogue reuse

  const int tid = threadIdx.x;
  const int wave = tid >> 6, lane = tid & 63;
  const int half = wave >> 1, wg = wave & 1;
  const int hh = lane >> 5, q5 = lane & 31;
  const int h = blockIdx.x, qb = blockIdx.y, b = blockIdx.z;
  const int q0 = qb * 128 + wg * 64;

  const size_t kbase = ((size_t)b * 2048) * 1024 + (size_t)h * 64;
  const size_t vbase = ((size_t)h * 64) * 4096 + (size_t)b * 2048;

  // Q B-frags for both q-groups (pre-scaled by SM_SCALE at LN)
  bf16x8 qf[2][4];
#pragma unroll
  for (int qg = 0; qg < 2; qg++){
    const size_t qrow = ((size_t)b * 2048 + q0 + qg * 32 + q5) * 1024 + (size_t)h * 64;
#pragma unroll
    for (int c = 0; c < 4; c++)
      qf[qg][c] = *(const bf16x8*)(Q + qrow + c * 16 + hh * 8);
  }

  f32x16 oacc[2][2];   // [qg][mt]
#pragma unroll
  for (int t = 0; t < 16; t++){
    oacc[0][0][t] = 0.f; oacc[0][1][t] = 0.f;
    oacc[1][0][t] = 0.f; oacc[1][1][t] = 0.f;
  }
  float lacc[2] = {0.f, 0.f};

  const int srow = lane >> 3;
  const int csrc = ((lane & 7) ^ srow) * 8;
  const int wr0 = wg * 32;

#define STAGE(bufi, kt)                                                         \
  {                                                                             \
    const short* ks = K + kbase + (size_t)((kt) * 64 + wr0 + srow) * 1024 + csrc; \
    const short* vs = Vt + vbase + (size_t)(wr0 + srow) * 4096 + (kt) * 64 + csrc; \
    short* kd = Ks  + (half * 2 + (bufi)) * 4096 + wr0 * 64;                    \
    short* vd = Vts + (half * 2 + (bufi)) * 4096 + wr0 * 64;                    \
    gl_lds16(ks,             kd);                                               \
    gl_lds16(ks +  8 * 1024, kd + 512);                                         \
    gl_lds16(ks + 16 * 1024, kd + 1024);                                        \
    gl_lds16(ks + 24 * 1024, kd + 1536);                                        \
    gl_lds16(vs,             vd);                                               \
    gl_lds16(vs +  8 * 4096, vd + 512);                                         \
    gl_lds16(vs + 16 * 4096, vd + 1024);                                        \
    gl_lds16(vs + 24 * 4096, vd + 1536);                                        \
  }

  STAGE(0, half)

  for (int i = 0; i < 16; i++){
    const int buf = i & 1;
    __syncthreads();                         // staging(buf) drained; buf^1 free
    if (i + 1 < 16) STAGE(buf ^ 1, 2 * (i + 1) + half)

    const short* kb_l = Ks  + (half * 2 + buf) * 4096;
    const short* vb_l = Vts + (half * 2 + buf) * 4096;

    // ---- hoist all 8 kf reads (q-independent) ----
    bf16x8 kf[2][4];
#pragma unroll
    for (int s32 = 0; s32 < 2; s32++){
      const int key = s32 * 32 + q5;
#pragma unroll
      for (int c = 0; c < 4; c++)
        kf[s32][c] = *(const bf16x8*)(&kb_l[key * 64 + (((2*c + hh) ^ (key & 7)) << 3)]);
    }

    // ---- S^T = K·Q^T for both q-groups: 4 independent MFMA chains ----
    f32x16 sacc[2][2];   // [qg][s32]
#pragma unroll
    for (int t = 0; t < 16; t++){
      sacc[0][0][t] = 0.f; sacc[0][1][t] = 0.f;
      sacc[1][0][t] = 0.f; sacc[1][1][t] = 0.f;
    }
#pragma unroll
    for (int c = 0; c < 4; c++){
      sacc[0][0] = __builtin_amdgcn_mfma_f32_32x32x16_bf16(kf[0][c], qf[0][c], sacc[0][0], 0, 0, 0);
      sacc[0][1] = __builtin_amdgcn_mfma_f32_32x32x16_bf16(kf[1][c], qf[0][c], sacc[0][1], 0, 0, 0);
      sacc[1][0] = __builtin_amdgcn_mfma_f32_32x32x16_bf16(kf[0][c], qf[1][c], sacc[1][0], 0, 0, 0);
      sacc[1][1] = __builtin_amdgcn_mfma_f32_32x32x16_bf16(kf[1][c], qf[1][c], sacc[1][1], 0, 0, 0);
    }

    // ---- P = exp2(S^T); pack to bf16; l via VALU partial trees ----
    bf16x8 pf[2][2][2];   // [qg][s32][c]
#pragma unroll
    for (int qg = 0; qg < 2; qg++){
#pragma unroll
      for (int s32 = 0; s32 < 2; s32++){
        unsigned int pu[16];
        float pp[4] = {0.f, 0.f, 0.f, 0.f};
#pragma unroll
        for (int t = 0; t < 16; t++){
          const float e = __builtin_amdgcn_exp2f(sacc[qg][s32][t]);
          pp[t & 3] += e;
          unsigned int u; __builtin_memcpy(&u, &e, 4);
          pu[t] = u + 0x8000u;               // round into top 16 bits
        }
        lacc[qg] += (pp[0] + pp[1]) + (pp[2] + pp[3]);
#pragma unroll
        for (int c = 0; c < 2; c++){
          u32x4 tmp;
          tmp[0] = __builtin_amdgcn_perm(pu[4*c + 1], pu[4*c + 0], 0x07060302u);
          tmp[1] = __builtin_amdgcn_perm(pu[4*c + 3], pu[4*c + 2], 0x07060302u);
          tmp[2] = __builtin_amdgcn_perm(pu[8 + 4*c + 1], pu[8 + 4*c + 0], 0x07060302u);
          tmp[3] = __builtin_amdgcn_perm(pu[8 + 4*c + 3], pu[8 + 4*c + 2], 0x07060302u);
          __builtin_memcpy(&pf[qg][s32][c], &tmp, 16);
        }
      }
    }

    // ---- O^T += V^T·P^T : vf read once, consumed by both q-groups ----
#pragma unroll
    for (int s32 = 0; s32 < 2; s32++){
#pragma unroll
      for (int c = 0; c < 2; c++){
#pragma unroll
        for (int mt = 0; mt < 2; mt++){
          const int d = mt * 32 + q5;
          bf16x8 vf = *(const bf16x8*)(&vb_l[d * 64 + (((s32*4 + 2*c + hh) ^ (d & 7)) << 3)]);
          oacc[0][mt] = __builtin_amdgcn_mfma_f32_32x32x16_bf16(vf, pf[0][s32][c], oacc[0][mt], 0, 0, 0);
          oacc[1][mt] = __builtin_amdgcn_mfma_f32_32x32x16_bf16(vf, pf[1][s32][c], oacc[1][mt], 0, 0, 0);
        }
      }
    }
  }

  // ---- combine halves through LDS, then store O[q][d] = O^T / l ----
  const int widx = wg * 64 + lane;           // 0..127
  __syncthreads();                           // all buffer reads done
#pragma unroll
  for (int qg = 0; qg < 2; qg++){
    const float lh = lacc[qg] + __shfl_xor(lacc[qg], 32);
    if (half == 1){
      float* base = scr + widx * 33;
#pragma unroll
      for (int t = 0; t < 16; t++){ base[t] = oacc[qg][0][t]; base[16 + t] = oacc[qg][1][t]; }
      scr[4224 + widx] = lh;
    }
    __syncthreads();
    if (half == 0){
      const float* base = scr + widx * 33;
      const float l2 = scr[4224 + widx];
      const float linv = 1.0f / (lh + l2);
      const size_t orow = ((size_t)b * 2048 + q0 + qg * 32 + q5) * 1024 + (size_t)h * 64;
#pragma unroll
      for (int mt = 0; mt < 2; mt++){
#pragma unroll
        for (int g = 0; g < 4; g++){
          bf16x4 o4;
#pragma unroll
          for (int u = 0; u < 4; u++)
            o4[u] = f2b((oacc[qg][mt][g*4 + u] + base[mt*16 + g*4 + u]) * linv);
          *(bf16x4*)(O + orow + mt*32 + g*8 + 4*hh) = o4;
        }
      }
    }
    __syncthreads();
  }
}
#undef STAGE

// ---------------------------------------------------------------------------
extern "C" void kernel_launch(void* const* d_in, const int* in_sizes, int n_in,
                              void* d_out, int out_size, void* d_ws, size_t ws_size,
                              hipStream_t stream) {
  const float* emb  = (const float*)d_in[0];
  const float* ctx  = (const float*)d_in[1];
  const float* Wq   = (const float*)d_in[2];
  const float* Wk   = (const float*)d_in[3];
  const float* Wv   = (const float*)d_in[4];
  const float* Wu   = (const float*)d_in[5];
  const float* bu   = (const float*)d_in[6];
  const float* qn_w = (const float*)d_in[7];
  const float* qn_b = (const float*)d_in[8];
  const float* kn_w = (const float*)d_in[9];
  const float* kn_b = (const float*)d_in[10];
  float* out = (float*)d_out;

  const size_t BIG = (size_t)4096 * 1024;
  const size_t WSZ = (size_t)1024 * 1024;
  short* ws   = (short*)d_ws;
  short* embh = ws;
  short* ctxh = embh + BIG;
  short* Wqh  = ctxh + BIG;
  short* Wkh  = Wqh + WSZ;
  short* Wvh  = Wkh + WSZ;
  short* Wuh  = Wvh + WSZ;
  short* qh   = Wuh + WSZ;
  short* kh   = qh + BIG;
  short* vth  = kh + BIG;    // V^T [inner][token], key-permuted columns
  short* aoh  = vth + BIG;

  cvt6_kernel<<<12288, 256, 0, stream>>>(emb, ctx, Wq, Wk, Wv, Wu,
                                         embh, ctxh, Wqh, Wkh, Wvh, Wuh);

  gemm_qkv_kernel<<<dim3(256, 3), 256, 0, stream>>>(
      embh, ctxh, Wqh, Wkh, Wvh, qh, kh, vth,
      qn_w, qn_b, kn_w, kn_b);

  flash2_kernel<<<dim3(16, 16, 2), 256, 0, stream>>>(qh, kh, vth, aoh);

  gemm_out_kernel<<<dim3(64, 16), 256, 0, stream>>>(aoh, Wuh, out, bu);
}